// Round 3
// baseline (623.673 us; speedup 1.0000x reference)
//
#include <hip/hip_runtime.h>
#include <cstdint>
#include <cfloat>

// CSR sparse retrieval: scores = CSR_docs · densify(query), then top-10.
//  1) score_kernel: grid-stride over nnz, int4-vectorized indice loads.
//     Per block: 3.8KB LDS bitmap of the ~32 query terms (hit rate ~0.1%).
//     On hit only: load values[j], sum matching query vals (dup coalescing),
//     binary-search crow for the row, atomicAdd into scores[doc].
//  2) topk_kernel<false>: 256 wave-blocks reduce 500K scores -> 2560 candidates.
//  3) topk_kernel<true>:  1 wave reduces 2560 -> top-10, writes d_out as
//     [10 scores, 10 doc-ids-as-float] (harness views tuple output as float*).

#define BM_WORDS 954          // ceil(30522/32)
#define TOPK     10
#define S1_BLOCKS 256
#define QCAP     64

__device__ __forceinline__ void score_hit(
    int id, int j, const uint32_t* bm, const int* s_qi, const float* s_qv,
    int qn, const int* __restrict__ crow, const float* __restrict__ values,
    int n_docs, float* __restrict__ scores)
{
    if ((bm[id >> 5] >> (id & 31)) & 1u) {
        float qv = 0.f;
        for (int q = 0; q < qn; ++q)
            if (s_qi[q] == id) qv += s_qv[q];
        const float prod = values[j] * qv;
        // upper_bound(crow, j) - 1
        int lo = 0, hi = n_docs + 1;
        while (lo < hi) {
            const int mid = (lo + hi) >> 1;
            if (crow[mid] <= j) lo = mid + 1; else hi = mid;
        }
        atomicAdd(&scores[lo - 1], prod);
    }
}

__global__ __launch_bounds__(256) void score_kernel(
    const int* __restrict__ q_idx, const float* __restrict__ q_val, int qn,
    const int* __restrict__ crow, const int* __restrict__ indice,
    const float* __restrict__ values, int nnz, int n_docs,
    float* __restrict__ scores)
{
    __shared__ uint32_t bm[BM_WORDS];
    __shared__ int   s_qi[QCAP];
    __shared__ float s_qv[QCAP];

    if (qn > QCAP) qn = QCAP;
    for (int i = threadIdx.x; i < BM_WORDS; i += blockDim.x) bm[i] = 0u;
    __syncthreads();
    for (int i = threadIdx.x; i < qn; i += blockDim.x) {
        const int qi = q_idx[i];
        s_qi[i] = qi;
        s_qv[i] = q_val[i];
        atomicOr(&bm[qi >> 5], 1u << (qi & 31));
    }
    __syncthreads();

    const int nnz4 = nnz >> 2;
    const int gtid = blockIdx.x * blockDim.x + threadIdx.x;
    const int gstride = gridDim.x * blockDim.x;
    const int4* __restrict__ ind4 = (const int4*)indice;

    for (int t = gtid; t < nnz4; t += gstride) {
        const int4 v = ind4[t];
        score_hit(v.x, t * 4 + 0, bm, s_qi, s_qv, qn, crow, values, n_docs, scores);
        score_hit(v.y, t * 4 + 1, bm, s_qi, s_qv, qn, crow, values, n_docs, scores);
        score_hit(v.z, t * 4 + 2, bm, s_qi, s_qv, qn, crow, values, n_docs, scores);
        score_hit(v.w, t * 4 + 3, bm, s_qi, s_qv, qn, crow, values, n_docs, scores);
    }
    if (gtid < (nnz & 3)) {                  // tail (nnz % 4 elements)
        const int j = (nnz & ~3) + gtid;
        score_hit(indice[j], j, bm, s_qi, s_qv, qn, crow, values, n_docs, scores);
    }
}

// One wave per block. Each lane keeps a personal top-10 in registers over its
// strided slice, then 10 rounds of 64-lane butterfly argmax (ties: smaller
// doc id) emit the block's top-10.
template <bool FINAL>
__global__ __launch_bounds__(64) void topk_kernel(
    const float* __restrict__ vals, const int* __restrict__ ids, int n,
    float* __restrict__ out_v, int* __restrict__ out_i)
{
    const int lane = threadIdx.x;
    float bv[TOPK];
    int   bi[TOPK];
    #pragma unroll
    for (int s = 0; s < TOPK; ++s) { bv[s] = -FLT_MAX; bi[s] = 0x7fffffff; }
    float vmin = -FLT_MAX;
    int   minslot = 0;

    const int start  = blockIdx.x * 64 + lane;
    const int stride = gridDim.x * 64;
    for (int i = start; i < n; i += stride) {
        const float v = vals[i];
        if (v > vmin) {
            bv[minslot] = v;
            bi[minslot] = ids ? ids[i] : i;
            vmin = bv[0]; minslot = 0;
            #pragma unroll
            for (int s = 1; s < TOPK; ++s)
                if (bv[s] < vmin) { vmin = bv[s]; minslot = s; }
        }
    }

    for (int r = 0; r < TOPK; ++r) {
        float lv = bv[0]; int ls = 0;
        #pragma unroll
        for (int s = 1; s < TOPK; ++s)
            if (bv[s] > lv || (bv[s] == lv && bi[s] < bi[ls])) { lv = bv[s]; ls = s; }
        float rv = lv; int rd = bi[ls]; int rl = lane;
        #pragma unroll
        for (int off = 32; off > 0; off >>= 1) {
            const float ov = __shfl_xor(rv, off);
            const int   od = __shfl_xor(rd, off);
            const int   ol = __shfl_xor(rl, off);
            if (ov > rv || (ov == rv && (od < rd || (od == rd && ol < rl)))) {
                rv = ov; rd = od; rl = ol;
            }
        }
        if (lane == rl) { bv[ls] = -FLT_MAX; bi[ls] = 0x7fffffff; }
        if (lane == 0) {
            if (FINAL) {
                out_v[r]        = rv;
                out_v[TOPK + r] = (float)rd;   // doc ids exactly representable (<2^24)
            } else {
                out_v[blockIdx.x * TOPK + r] = rv;
                out_i[blockIdx.x * TOPK + r] = rd;
            }
        }
    }
}

extern "C" void kernel_launch(void* const* d_in, const int* in_sizes, int n_in,
                              void* d_out, int out_size, void* d_ws, size_t ws_size,
                              hipStream_t stream) {
    const int*   q_idx  = (const int*)  d_in[0];
    const float* q_val  = (const float*)d_in[1];
    const int*   crow   = (const int*)  d_in[2];
    const int*   indice = (const int*)  d_in[3];
    const float* values = (const float*)d_in[4];
    const int qn     = in_sizes[0];
    const int n_docs = in_sizes[2] - 1;
    const int nnz    = in_sizes[3];

    // workspace: scores (n_docs f32) | candv (2560 f32) | candi (2560 i32)
    char* ws = (char*)d_ws;
    float* scores = (float*)ws;
    size_t off = ((size_t)n_docs * sizeof(float) + 255) & ~(size_t)255;
    float* candv = (float*)(ws + off);
    int*   candi = (int*)(ws + off + S1_BLOCKS * TOPK * sizeof(float));

    hipMemsetAsync(scores, 0, (size_t)n_docs * sizeof(float), stream);

    score_kernel<<<2048, 256, 0, stream>>>(q_idx, q_val, qn, crow, indice,
                                           values, nnz, n_docs, scores);

    topk_kernel<false><<<S1_BLOCKS, 64, 0, stream>>>(scores, nullptr, n_docs,
                                                     candv, candi);
    topk_kernel<true><<<1, 64, 0, stream>>>(candv, candi, S1_BLOCKS * TOPK,
                                            (float*)d_out, nullptr);
}

// Round 4
// 606.841 us; speedup vs baseline: 1.0277x; 1.0277x over previous
//
#include <hip/hip_runtime.h>
#include <cstdint>
#include <cfloat>

// CSR sparse retrieval: scores = CSR_docs · densify(query), then top-10.
//  1) score_docs_kernel: ONE WAVE PER DOC. crow[d],crow[d+1] read directly
//     (no binary search, no atomics, no memset — every scores[d] is written).
//     Row len <= 192 fast path: 3 independent masked index loads (MLP),
//     LDS bitmap probe (hit rate ~0.1%), values[] loaded only on hit,
//     butterfly wave-reduce, lane0 stores scores[d]. Next-doc crow prefetch
//     software-pipelined over current-doc processing.
//  2) topk_kernel<false>: 256 wave-blocks reduce 500K scores -> 2560 cands.
//  3) topk_kernel<true>:  1 wave reduces 2560 -> top-10; d_out =
//     [10 scores, 10 doc-ids-as-float].

#define BM_WORDS 954          // ceil(30522/32)
#define TOPK     10
#define S1_BLOCKS 256
#define QCAP     64
#define SCORE_BLOCKS 2048

__global__ __launch_bounds__(256) void score_docs_kernel(
    const int* __restrict__ q_idx, const float* __restrict__ q_val, int qn,
    const int* __restrict__ crow, const int* __restrict__ indice,
    const float* __restrict__ values, int n_docs, int docs_per_block,
    float* __restrict__ scores)
{
    __shared__ uint32_t bm[BM_WORDS];
    __shared__ int   s_qi[QCAP];
    __shared__ float s_qv[QCAP];

    if (qn > QCAP) qn = QCAP;
    for (int i = threadIdx.x; i < BM_WORDS; i += 256) bm[i] = 0u;
    __syncthreads();
    if (threadIdx.x < qn) {
        const int qi = q_idx[threadIdx.x];
        s_qi[threadIdx.x] = qi;
        s_qv[threadIdx.x] = q_val[threadIdx.x];
        atomicOr(&bm[qi >> 5], 1u << (qi & 31));
    }
    __syncthreads();

    const int wave = threadIdx.x >> 6;
    const int lane = threadIdx.x & 63;
    const int d0 = blockIdx.x * docs_per_block;
    const int d1 = min(d0 + docs_per_block, n_docs);

    int d = d0 + wave;
    // prefetched row bounds for current doc
    int s = 0, e = 0;
    if (d < d1) { s = crow[d]; e = crow[d + 1]; }

    while (d < d1) {
        // issue next doc's crow loads early (overlap with this row's work)
        const int dn = d + 4;
        int sn = 0, en = 0;
        if (dn < d1) { sn = crow[dn]; en = crow[dn + 1]; }

        float acc = 0.f;
        const int len = e - s;
        if (len <= 192) {
            // up to 3 independent masked loads in flight
            const int j0 = s + lane, j1 = j0 + 64, j2 = j1 + 64;
            const bool m0 = j0 < e, m1 = j1 < e, m2 = j2 < e;
            const int id0 = m0 ? indice[j0] : 0;
            const int id1 = m1 ? indice[j1] : 0;
            const int id2 = m2 ? indice[j2] : 0;
            if (m0 && ((bm[id0 >> 5] >> (id0 & 31)) & 1u)) {
                float qv = 0.f;
                for (int q = 0; q < qn; ++q) if (s_qi[q] == id0) qv += s_qv[q];
                acc += values[j0] * qv;
            }
            if (m1 && ((bm[id1 >> 5] >> (id1 & 31)) & 1u)) {
                float qv = 0.f;
                for (int q = 0; q < qn; ++q) if (s_qi[q] == id1) qv += s_qv[q];
                acc += values[j1] * qv;
            }
            if (m2 && ((bm[id2 >> 5] >> (id2 & 31)) & 1u)) {
                float qv = 0.f;
                for (int q = 0; q < qn; ++q) if (s_qi[q] == id2) qv += s_qv[q];
                acc += values[j2] * qv;
            }
        } else {
            for (int j = s + lane; j < e; j += 64) {
                const int id = indice[j];
                if ((bm[id >> 5] >> (id & 31)) & 1u) {
                    float qv = 0.f;
                    for (int q = 0; q < qn; ++q) if (s_qi[q] == id) qv += s_qv[q];
                    acc += values[j] * qv;
                }
            }
        }
        #pragma unroll
        for (int off = 32; off; off >>= 1) acc += __shfl_xor(acc, off);
        if (lane == 0) scores[d] = acc;

        d = dn; s = sn; e = en;
    }
}

// One wave per block. Each lane keeps a personal top-10 in registers over its
// strided slice, then 10 rounds of 64-lane butterfly argmax (ties: smaller
// doc id) emit the block's top-10.  (unchanged — proven correct)
template <bool FINAL>
__global__ __launch_bounds__(64) void topk_kernel(
    const float* __restrict__ vals, const int* __restrict__ ids, int n,
    float* __restrict__ out_v, int* __restrict__ out_i)
{
    const int lane = threadIdx.x;
    float bv[TOPK];
    int   bi[TOPK];
    #pragma unroll
    for (int s = 0; s < TOPK; ++s) { bv[s] = -FLT_MAX; bi[s] = 0x7fffffff; }
    float vmin = -FLT_MAX;
    int   minslot = 0;

    const int start  = blockIdx.x * 64 + lane;
    const int stride = gridDim.x * 64;
    for (int i = start; i < n; i += stride) {
        const float v = vals[i];
        if (v > vmin) {
            bv[minslot] = v;
            bi[minslot] = ids ? ids[i] : i;
            vmin = bv[0]; minslot = 0;
            #pragma unroll
            for (int s = 1; s < TOPK; ++s)
                if (bv[s] < vmin) { vmin = bv[s]; minslot = s; }
        }
    }

    for (int r = 0; r < TOPK; ++r) {
        float lv = bv[0]; int ls = 0;
        #pragma unroll
        for (int s = 1; s < TOPK; ++s)
            if (bv[s] > lv || (bv[s] == lv && bi[s] < bi[ls])) { lv = bv[s]; ls = s; }
        float rv = lv; int rd = bi[ls]; int rl = lane;
        #pragma unroll
        for (int off = 32; off > 0; off >>= 1) {
            const float ov = __shfl_xor(rv, off);
            const int   od = __shfl_xor(rd, off);
            const int   ol = __shfl_xor(rl, off);
            if (ov > rv || (ov == rv && (od < rd || (od == rd && ol < rl)))) {
                rv = ov; rd = od; rl = ol;
            }
        }
        if (lane == rl) { bv[ls] = -FLT_MAX; bi[ls] = 0x7fffffff; }
        if (lane == 0) {
            if (FINAL) {
                out_v[r]        = rv;
                out_v[TOPK + r] = (float)rd;   // doc ids exactly representable (<2^24)
            } else {
                out_v[blockIdx.x * TOPK + r] = rv;
                out_i[blockIdx.x * TOPK + r] = rd;
            }
        }
    }
}

extern "C" void kernel_launch(void* const* d_in, const int* in_sizes, int n_in,
                              void* d_out, int out_size, void* d_ws, size_t ws_size,
                              hipStream_t stream) {
    const int*   q_idx  = (const int*)  d_in[0];
    const float* q_val  = (const float*)d_in[1];
    const int*   crow   = (const int*)  d_in[2];
    const int*   indice = (const int*)  d_in[3];
    const float* values = (const float*)d_in[4];
    const int qn     = in_sizes[0];
    const int n_docs = in_sizes[2] - 1;

    // workspace: scores (n_docs f32) | candv (2560 f32) | candi (2560 i32)
    char* ws = (char*)d_ws;
    float* scores = (float*)ws;
    size_t off = ((size_t)n_docs * sizeof(float) + 255) & ~(size_t)255;
    float* candv = (float*)(ws + off);
    int*   candi = (int*)(ws + off + S1_BLOCKS * TOPK * sizeof(float));

    const int docs_per_block = (n_docs + SCORE_BLOCKS - 1) / SCORE_BLOCKS;
    score_docs_kernel<<<SCORE_BLOCKS, 256, 0, stream>>>(
        q_idx, q_val, qn, crow, indice, values, n_docs, docs_per_block, scores);

    topk_kernel<false><<<S1_BLOCKS, 64, 0, stream>>>(scores, nullptr, n_docs,
                                                     candv, candi);
    topk_kernel<true><<<1, 64, 0, stream>>>(candv, candi, S1_BLOCKS * TOPK,
                                            (float*)d_out, nullptr);
}